// Round 11
// baseline (974.746 us; speedup 1.0000x reference)
//
#include <hip/hip_runtime.h>

// Problem constants (match reference setup_inputs)
#define NB    50000   // nodes
#define BB    64      // batch  (== wavefront size: lane = b)
#define DD    16      // neighbors per node
#define NDRVN 1000    // driver nodes

typedef float f2 __attribute__((ext_vector_type(2)));

// ---------------------------------------------------------------------------
// Force a (uniform) value into a VGPR.  Measured (R4->R5): fma with an SGPR
// broadcast operand issues at ~half the all-VGPR rate on gfx950.
__device__ __forceinline__ float vg(float s) {
    asm("" : "+v"(s));
    return s;
}
__device__ __forceinline__ f2 splat2(float s) {
    float v = vg(s);
    f2 r; r.x = v; r.y = v;
    return r;
}
__device__ __forceinline__ f2 pf(f2 a, f2 b, f2 c) {
    return __builtin_elementwise_fma(a, b, c);        // v_pk_fma_f32
}
__device__ __forceinline__ f2 relu2(f2 a) {
    return __builtin_elementwise_max(a, (f2)0.0f);    // v_pk_max_f32
}

// ---------------------------------------------------------------------------
// Transpose x (B,N) -> z0 (N,B).
__global__ __launch_bounds__(256) void transpose_kernel(
    const float* __restrict__ x, float* __restrict__ xT)
{
    int tid = blockIdx.x * 256 + threadIdx.x;   // tid = n*64 + b
    int n = tid >> 6;
    int b = tid & 63;
    if (n < NB) xT[tid] = x[b * NB + n];
}

// ---------------------------------------------------------------------------
// One 5->5 conv1x3+relu layer, x-packed: activations held as f2 pairs
// {h[2j], h[2j+1]} per channel.  Pair count PIN -> POUT = PIN-1.
// Per (c, j, ci): k=0 and k=2 are aligned-pair pk_fma (weight splats);
// the misaligned k=1 term is 2 scalar fmacs on the pair's components.
// 4 insts / 6 MACs vs 6 scalar.  Liveness identical to the scalar version.
template<int PIN>
__device__ __forceinline__ void conv5x(const f2 (&in)[5][8], f2 (&out)[5][8],
                                       const float* __restrict__ w,
                                       const float* __restrict__ bias)
{
    constexpr int POUT = PIN - 1;
#pragma unroll
    for (int c = 0; c < 5; ++c) {
        f2 w0s[5], w2s[5];
        float w1s[5];
#pragma unroll
        for (int ci = 0; ci < 5; ++ci) {
            w0s[ci] = splat2(w[c * 15 + ci * 3 + 0]);
            w1s[ci] = vg(w[c * 15 + ci * 3 + 1]);
            w2s[ci] = splat2(w[c * 15 + ci * 3 + 2]);
        }
        float bc = vg(bias[c]);
        f2 bcc; bcc.x = bc; bcc.y = bc;
#pragma unroll
        for (int j = 0; j < POUT; ++j) {
            f2 acc = bcc;
#pragma unroll
            for (int ci = 0; ci < 5; ++ci) {
                acc = pf(w0s[ci], in[ci][j], acc);       // {w0*in[2j],   w0*in[2j+1]}
                acc = pf(w2s[ci], in[ci][j + 1], acc);   // {w2*in[2j+2], w2*in[2j+3]}
                acc.x = fmaf(w1s[ci], in[ci][j].y,     acc.x);  // w1*in[2j+1]
                acc.y = fmaf(w1s[ci], in[ci][j + 1].x, acc.y);  // w1*in[2j+2]
            }
            out[c][j] = relu2(acc);
        }
    }
}

// ---------------------------------------------------------------------------
// One full pass: gather 16 neighbors into 8 f2 pairs, run the 7-layer CNN
// x-packed in pure fp32 (fp16 is numerically dead: this net amplifies
// rounding noise ~400x, measured R10), pair-average, store.
// Wave = one node n (uniform), lane = batch index b.  z layout (N, B).
__global__ __launch_bounds__(256)
__attribute__((amdgpu_waves_per_eu(2, 8)))
void pass_kernel(
    const float* __restrict__ zin, float* __restrict__ zout,
    const int*  __restrict__ nidx,
    const float* __restrict__ w0, const float* __restrict__ b0,
    const float* __restrict__ w1, const float* __restrict__ b1,
    const float* __restrict__ w2, const float* __restrict__ b2,
    const float* __restrict__ w3, const float* __restrict__ b3,
    const float* __restrict__ w4, const float* __restrict__ b4,
    const float* __restrict__ w5, const float* __restrict__ b5,
    const float* __restrict__ w6, const float* __restrict__ b6)
{
    int tid  = blockIdx.x * 256 + threadIdx.x;
    int lane = tid & 63;
    // grid is exact (N*B == 12500*256) so every wave is full; force n uniform
    int n = __builtin_amdgcn_readfirstlane(tid >> 6);

    const int* ip = nidx + n * DD;

    // Gather into x-pairs: 16 fully-coalesced 256B loads.
    f2 g[8];
#pragma unroll
    for (int d = 0; d < 8; ++d) {
        g[d].x = zin[(size_t)ip[2 * d]     * BB + lane];
        g[d].y = zin[(size_t)ip[2 * d + 1] * BB + lane];
    }

    f2 hA[5][8], hB[5][8];

    // Layer 0: 1 -> 5 channels, width 16 -> 14 (8 -> 7 pairs)
#pragma unroll
    for (int c = 0; c < 5; ++c) {
        f2 w0s = splat2(w0[c * 3 + 0]);
        float w1m = vg(w0[c * 3 + 1]);
        f2 w2s = splat2(w0[c * 3 + 2]);
        float bc = vg(b0[c]);
        f2 bcc; bcc.x = bc; bcc.y = bc;
#pragma unroll
        for (int j = 0; j < 7; ++j) {
            f2 acc = bcc;
            acc = pf(w0s, g[j], acc);
            acc = pf(w2s, g[j + 1], acc);
            acc.x = fmaf(w1m, g[j].y,     acc.x);
            acc.y = fmaf(w1m, g[j + 1].x, acc.y);
            hA[c][j] = relu2(acc);
        }
    }

    conv5x<7>(hA, hB, w1, b1);   // 14 -> 12 (7 -> 6 pairs)
    conv5x<6>(hB, hA, w2, b2);   // 12 -> 10
    conv5x<5>(hA, hB, w3, b3);   // 10 -> 8
    conv5x<4>(hB, hA, w4, b4);   // 8  -> 6
    conv5x<3>(hA, hB, w5, b5);   // 6  -> 4 (2 pairs)

    // Layer 6: 5 -> 1, width 4 -> 2 (one pair), then pair-average.
    {
        float bc = vg(b6[0]);
        f2 acc; acc.x = bc; acc.y = bc;
#pragma unroll
        for (int ci = 0; ci < 5; ++ci) {
            f2 w0s = splat2(w6[ci * 3 + 0]);
            float w1m = vg(w6[ci * 3 + 1]);
            f2 w2s = splat2(w6[ci * 3 + 2]);
            acc = pf(w0s, hB[ci][0], acc);   // {w0*in0, w0*in1}
            acc = pf(w2s, hB[ci][1], acc);   // {w2*in2, w2*in3}
            acc.x = fmaf(w1m, hB[ci][0].y, acc.x);  // w1*in1
            acc.y = fmaf(w1m, hB[ci][1].x, acc.y);  // w1*in2
        }
        acc = relu2(acc);
        zout[(size_t)n * BB + lane] = 0.5f * (acc.x + acc.y);
    }
}

// ---------------------------------------------------------------------------
// Final driver gather: out[b, i] = z[driver_idx[i], b]   (out is (B, NDRV))
__global__ __launch_bounds__(256) void gather_out_kernel(
    const float* __restrict__ z, const int* __restrict__ didx,
    float* __restrict__ out)
{
    int i = blockIdx.x * 256 + threadIdx.x;
    if (i >= BB * NDRVN) return;
    int b = i / NDRVN;
    int k = i - b * NDRVN;
    out[i] = z[(size_t)didx[k] * BB + b];
}

// ---------------------------------------------------------------------------
extern "C" void kernel_launch(void* const* d_in, const int* in_sizes, int n_in,
                              void* d_out, int out_size, void* d_ws, size_t ws_size,
                              hipStream_t stream)
{
    const float* x    = (const float*)d_in[0];
    const int*   nidx = (const int*)  d_in[1];
    const int*   didx = (const int*)  d_in[2];
    const float* w[7];
    const float* b[7];
    for (int i = 0; i < 7; ++i) {
        w[i] = (const float*)d_in[3 + 2 * i];
        b[i] = (const float*)d_in[4 + 2 * i];
    }

    // Workspace: two ping-pong z buffers in (N, B) layout, 12.8 MB each.
    float* z0 = (float*)d_ws;
    float* z1 = z0 + (size_t)NB * BB;

    const int blocks = (NB * BB) / 256;   // 12500, exact

    transpose_kernel<<<blocks, 256, 0, stream>>>(x, z0);

    pass_kernel<<<blocks, 256, 0, stream>>>(z0, z1, nidx,
        w[0], b[0], w[1], b[1], w[2], b[2], w[3], b[3],
        w[4], b[4], w[5], b[5], w[6], b[6]);
    pass_kernel<<<blocks, 256, 0, stream>>>(z1, z0, nidx,
        w[0], b[0], w[1], b[1], w[2], b[2], w[3], b[3],
        w[4], b[4], w[5], b[5], w[6], b[6]);
    pass_kernel<<<blocks, 256, 0, stream>>>(z0, z1, nidx,
        w[0], b[0], w[1], b[1], w[2], b[2], w[3], b[3],
        w[4], b[4], w[5], b[5], w[6], b[6]);
    pass_kernel<<<blocks, 256, 0, stream>>>(z1, z0, nidx,
        w[0], b[0], w[1], b[1], w[2], b[2], w[3], b[3],
        w[4], b[4], w[5], b[5], w[6], b[6]);

    gather_out_kernel<<<(BB * NDRVN + 255) / 256, 256, 0, stream>>>(z0, didx, (float*)d_out);
}

// Round 12
// 943.510 us; speedup vs baseline: 1.0331x; 1.0331x over previous
//
#include <hip/hip_runtime.h>

// Problem constants (match reference setup_inputs)
#define NB    50000   // nodes
#define BB    64      // batch  (== wavefront size: lane = b)
#define DD    16      // neighbors per node
#define NDRVN 1000    // driver nodes

// ---------------------------------------------------------------------------
// Force a (uniform) value into a VGPR.  Measured (R4->R5): fma with an SGPR
// broadcast operand issues at ~half the all-VGPR rate on gfx950.
__device__ __forceinline__ float vg(float s) {
    asm("" : "+v"(s));
    return s;
}

// ---------------------------------------------------------------------------
// Transpose x (B,N) -> z0 (N,B).
__global__ __launch_bounds__(256) void transpose_kernel(
    const float* __restrict__ x, float* __restrict__ xT)
{
    int tid = blockIdx.x * 256 + threadIdx.x;   // tid = n*64 + b
    int n = tid >> 6;
    int b = tid & 63;
    if (n < NB) xT[tid] = x[b * NB + n];
}

// ---------------------------------------------------------------------------
// Pack mid-layer weights into a 16-float-per-channel aligned table so the
// pass kernel can fetch them as float4 VMEM loads (defeating both the
// s_load scalarization AND the 436 v_mov pins per wave of R5-R11):
//   wpk[(l-1)*80 + c*16 + k] = w_l[c][k]  (k<15, pad 0)   l = 1..5
//   wpk[400 + k]             = w6[k]      (k<15, pad 0)
//   wpk[432 + (l-1)*5 + c]   = b_l[c]                     l = 1..5
//   wpk[457]                 = b6[0]
__global__ void prep_kernel(
    const float* __restrict__ w1, const float* __restrict__ w2,
    const float* __restrict__ w3, const float* __restrict__ w4,
    const float* __restrict__ w5, const float* __restrict__ w6,
    const float* __restrict__ b1, const float* __restrict__ b2,
    const float* __restrict__ b3, const float* __restrict__ b4,
    const float* __restrict__ b5, const float* __restrict__ b6,
    float* __restrict__ wpk)
{
    int t = threadIdx.x;
    if (t >= 512) return;
    const float* ws[5] = {w1, w2, w3, w4, w5};
    const float* bs[5] = {b1, b2, b3, b4, b5};
    float val = 0.0f;
    if (t < 400) {
        int l = t / 80, r = t % 80, c = r / 16, k = r % 16;
        if (k < 15) val = ws[l][c * 15 + k];
    } else if (t < 416) {
        int k = t - 400;
        if (k < 15) val = w6[k];
    } else if (t >= 432 && t < 457) {
        int i = t - 432;
        val = bs[i / 5][i % 5];
    } else if (t == 457) {
        val = b6[0];
    }
    wpk[t] = val;
}

// ---------------------------------------------------------------------------
// One 5->5 conv1x3 + relu layer, fully unrolled.  Weights arrive as 4 float4
// VMEM loads per output channel (all lanes same address -> L1 broadcast;
// divz is a runtime 0 the compiler can't prove uniform, forcing VMEM).
// Zero v_mov pins, zero SGPR-operand fmas, no layer-boundary s_load waits.
template<int WOUT>
__device__ __forceinline__ void conv5v(const float (&in)[5][14], float (&out)[5][14],
                                       const float4* __restrict__ wl,
                                       const float* __restrict__ bl,
                                       int divz, int lane)
{
#pragma unroll
    for (int c = 0; c < 5; ++c) {
        float4 a0 = wl[c * 4 + 0 + (lane & divz)];
        float4 a1 = wl[c * 4 + 1 + (lane & divz)];
        float4 a2 = wl[c * 4 + 2 + (lane & divz)];
        float4 a3 = wl[c * 4 + 3 + (lane & divz)];
        float wr[15] = {a0.x, a0.y, a0.z, a0.w,
                        a1.x, a1.y, a1.z, a1.w,
                        a2.x, a2.y, a2.z, a2.w,
                        a3.x, a3.y, a3.z};
        float bc = bl[c + (lane & divz)];
#pragma unroll
        for (int x = 0; x < WOUT; ++x) {
            float acc = bc;
#pragma unroll
            for (int ci = 0; ci < 5; ++ci) {
                acc = fmaf(wr[ci * 3 + 0], in[ci][x + 0], acc);
                acc = fmaf(wr[ci * 3 + 1], in[ci][x + 1], acc);
                acc = fmaf(wr[ci * 3 + 2], in[ci][x + 2], acc);
            }
            out[c][x] = fmaxf(acc, 0.0f);
        }
    }
}

// ---------------------------------------------------------------------------
// One full pass: gather 16 neighbors, run the 7-layer CNN, pair-average.
// Wave = one node n (uniform), lane = batch index b.  z layout (N, B).
// Identical structure to R7 (250.5 us/pass); only change: mid-layer weights
// + biases come from the packed table via float4 VMEM broadcast loads.
__global__ __launch_bounds__(256)
__attribute__((amdgpu_waves_per_eu(2, 8)))
void pass_kernel(
    const float* __restrict__ zin, float* __restrict__ zout,
    const int*  __restrict__ nidx,
    const float* __restrict__ wpk,
    const float* __restrict__ w0, const float* __restrict__ b0,
    int divz)
{
    int tid  = blockIdx.x * 256 + threadIdx.x;
    int lane = tid & 63;
    // grid is exact (N*B == 12500*256) so every wave is full; force n uniform
    int n = __builtin_amdgcn_readfirstlane(tid >> 6);

    const float4* w4 = (const float4*)wpk;
    const float*  bp = wpk + 432;

    // Neighbor indices: wave-uniform addresses -> s_load into SGPRs.
    const int* ip = nidx + n * DD;

    // Gather: 16 fully-coalesced 256B loads (uniform base + lane*4).
    float g[16];
#pragma unroll
    for (int d = 0; d < 16; ++d) {
        int j = ip[d];
        g[d] = zin[(size_t)j * BB + lane];
    }

    float ha[5][14], hb[5][14];

    // Layer 0: 1 -> 5 channels, width 16 -> 14 (15 weights: s_load + pin)
#pragma unroll
    for (int c = 0; c < 5; ++c) {
        float wa = vg(w0[c * 3 + 0]), wb = vg(w0[c * 3 + 1]), wc = vg(w0[c * 3 + 2]);
        float bc = vg(b0[c]);
#pragma unroll
        for (int x = 0; x < 14; ++x) {
            float acc = bc;
            acc = fmaf(wa, g[x + 0], acc);
            acc = fmaf(wb, g[x + 1], acc);
            acc = fmaf(wc, g[x + 2], acc);
            ha[c][x] = fmaxf(acc, 0.0f);
        }
    }

    conv5v<12>(ha, hb, w4 +  0, bp +  0, divz, lane);   // 14 -> 12
    conv5v<10>(hb, ha, w4 + 20, bp +  5, divz, lane);   // 12 -> 10
    conv5v<8> (ha, hb, w4 + 40, bp + 10, divz, lane);   // 10 -> 8
    conv5v<6> (hb, ha, w4 + 60, bp + 15, divz, lane);   // 8  -> 6
    conv5v<4> (ha, hb, w4 + 80, bp + 20, divz, lane);   // 6  -> 4

    // Layer 6: 5 -> 1, width 4 -> 2
    {
        float4 a0 = w4[100 + (lane & divz)];
        float4 a1 = w4[101 + (lane & divz)];
        float4 a2 = w4[102 + (lane & divz)];
        float4 a3 = w4[103 + (lane & divz)];
        float wr[15] = {a0.x, a0.y, a0.z, a0.w,
                        a1.x, a1.y, a1.z, a1.w,
                        a2.x, a2.y, a2.z, a2.w,
                        a3.x, a3.y, a3.z};
        float bc = bp[25 + (lane & divz)];
        float t0 = bc, t1 = bc;
#pragma unroll
        for (int ci = 0; ci < 5; ++ci) {
            t0 = fmaf(wr[ci * 3 + 0], hb[ci][0], t0);
            t0 = fmaf(wr[ci * 3 + 1], hb[ci][1], t0);
            t0 = fmaf(wr[ci * 3 + 2], hb[ci][2], t0);
            t1 = fmaf(wr[ci * 3 + 0], hb[ci][1], t1);
            t1 = fmaf(wr[ci * 3 + 1], hb[ci][2], t1);
            t1 = fmaf(wr[ci * 3 + 2], hb[ci][3], t1);
        }
        t0 = fmaxf(t0, 0.0f);
        t1 = fmaxf(t1, 0.0f);
        zout[(size_t)n * BB + lane] = 0.5f * (t0 + t1);
    }
}

// ---------------------------------------------------------------------------
// Final driver gather: out[b, i] = z[driver_idx[i], b]   (out is (B, NDRV))
__global__ __launch_bounds__(256) void gather_out_kernel(
    const float* __restrict__ z, const int* __restrict__ didx,
    float* __restrict__ out)
{
    int i = blockIdx.x * 256 + threadIdx.x;
    if (i >= BB * NDRVN) return;
    int b = i / NDRVN;
    int k = i - b * NDRVN;
    out[i] = z[(size_t)didx[k] * BB + b];
}

// ---------------------------------------------------------------------------
extern "C" void kernel_launch(void* const* d_in, const int* in_sizes, int n_in,
                              void* d_out, int out_size, void* d_ws, size_t ws_size,
                              hipStream_t stream)
{
    const float* x    = (const float*)d_in[0];
    const int*   nidx = (const int*)  d_in[1];
    const int*   didx = (const int*)  d_in[2];
    const float* w[7];
    const float* b[7];
    for (int i = 0; i < 7; ++i) {
        w[i] = (const float*)d_in[3 + 2 * i];
        b[i] = (const float*)d_in[4 + 2 * i];
    }

    // Workspace: two ping-pong z buffers (N,B) + packed weight table (512 f).
    float* z0  = (float*)d_ws;
    float* z1  = z0 + (size_t)NB * BB;
    float* wpk = z1 + (size_t)NB * BB;

    const int blocks = (NB * BB) / 256;   // 12500, exact
    const int divz = 0;                   // runtime zero: forces VMEM weight loads

    prep_kernel<<<1, 512, 0, stream>>>(w[1], w[2], w[3], w[4], w[5], w[6],
                                       b[1], b[2], b[3], b[4], b[5], b[6], wpk);
    transpose_kernel<<<blocks, 256, 0, stream>>>(x, z0);

    pass_kernel<<<blocks, 256, 0, stream>>>(z0, z1, nidx, wpk, w[0], b[0], divz);
    pass_kernel<<<blocks, 256, 0, stream>>>(z1, z0, nidx, wpk, w[0], b[0], divz);
    pass_kernel<<<blocks, 256, 0, stream>>>(z0, z1, nidx, wpk, w[0], b[0], divz);
    pass_kernel<<<blocks, 256, 0, stream>>>(z1, z0, nidx, wpk, w[0], b[0], divz);

    gather_out_kernel<<<(BB * NDRVN + 255) / 256, 256, 0, stream>>>(z0, didx, (float*)d_out);
}

// Round 13
// 903.349 us; speedup vs baseline: 1.0790x; 1.0445x over previous
//
#include <hip/hip_runtime.h>

// Problem constants (match reference setup_inputs)
#define NB    50000   // nodes
#define BB    64      // batch  (== wavefront size: lane = b)
#define DD    16      // neighbors per node
#define NDRVN 1000    // driver nodes

// ---------------------------------------------------------------------------
// Force a (uniform) value into a VGPR.  Measured (R4->R5): fma with an SGPR
// broadcast operand issues at ~half the all-VGPR rate on gfx950.
__device__ __forceinline__ float vg(float s) {
    asm("" : "+v"(s));
    return s;
}

// ---------------------------------------------------------------------------
// Transpose x (B,N) -> z0 (N,B).
__global__ __launch_bounds__(256) void transpose_kernel(
    const float* __restrict__ x, float* __restrict__ xT)
{
    int tid = blockIdx.x * 256 + threadIdx.x;   // tid = n*64 + b
    int n = tid >> 6;
    int b = tid & 63;
    if (n < NB) xT[tid] = x[b * NB + n];
}

// ---------------------------------------------------------------------------
// One 5->5 conv1x3 + relu layer, fully unrolled.  Weights/bias loaded scalar
// (uniform address) then pinned into VGPRs once per output-channel row; the
// 15-fma accumulation chain is then pure VOP2 v_fmac_f32.
template<int WOUT>
__device__ __forceinline__ void conv5(const float (&in)[5][14], float (&out)[5][14],
                                      const float* __restrict__ w,
                                      const float* __restrict__ bias)
{
#pragma unroll
    for (int c = 0; c < 5; ++c) {
        float wr[15];
#pragma unroll
        for (int t = 0; t < 15; ++t) wr[t] = vg(w[c * 15 + t]);
        float bc = vg(bias[c]);
#pragma unroll
        for (int x = 0; x < WOUT; ++x) {
            float acc = bc;
#pragma unroll
            for (int ci = 0; ci < 5; ++ci) {
                acc = fmaf(wr[ci * 3 + 0], in[ci][x + 0], acc);
                acc = fmaf(wr[ci * 3 + 1], in[ci][x + 1], acc);
                acc = fmaf(wr[ci * 3 + 2], in[ci][x + 2], acc);
            }
            out[c][x] = fmaxf(acc, 0.0f);
        }
    }
}

// ---------------------------------------------------------------------------
// One full pass: gather 16 neighbors, run the 7-layer CNN, pair-average.
// Wave = one node n (uniform), lane = batch index b.  z layout (N, B).
//
// CHAMPION CONFIG (R7, bench 896.9 us total = ~99% of the composed measured
// ceiling): fp32 end-to-end (sub-fp32 storage fails: net amplifies rounding
// noise ~400x, measured R9/R10), VGPR-pinned weights (SGPR-operand fma is
// half-rate, measured R4->R5), waves_per_eu(2,8) = 256-reg RA budget with
// uncapped hardware occupancy.  The fp32 VALU pipe runs at its measured
// ~103 TF (3.05 cyc/inst, m07) -- this kernel sits at ~93 TF effective with
// gather/relu/store included.
__global__ __launch_bounds__(256)
__attribute__((amdgpu_waves_per_eu(2, 8)))
void pass_kernel(
    const float* __restrict__ zin, float* __restrict__ zout,
    const int*  __restrict__ nidx,
    const float* __restrict__ w0, const float* __restrict__ b0,
    const float* __restrict__ w1, const float* __restrict__ b1,
    const float* __restrict__ w2, const float* __restrict__ b2,
    const float* __restrict__ w3, const float* __restrict__ b3,
    const float* __restrict__ w4, const float* __restrict__ b4,
    const float* __restrict__ w5, const float* __restrict__ b5,
    const float* __restrict__ w6, const float* __restrict__ b6)
{
    int tid  = blockIdx.x * 256 + threadIdx.x;
    int lane = tid & 63;
    // grid is exact (N*B == 12500*256) so every wave is full; force n uniform
    int n = __builtin_amdgcn_readfirstlane(tid >> 6);

    // Neighbor indices: wave-uniform addresses -> s_load into SGPRs.
    const int* ip = nidx + n * DD;

    // Gather: 16 fully-coalesced 256B loads (uniform base + lane*4).
    float g[16];
#pragma unroll
    for (int d = 0; d < 16; ++d) {
        int j = ip[d];
        g[d] = zin[(size_t)j * BB + lane];
    }

    float ha[5][14], hb[5][14];

    // Layer 0: 1 -> 5 channels, width 16 -> 14
#pragma unroll
    for (int c = 0; c < 5; ++c) {
        float wa = vg(w0[c * 3 + 0]), wb = vg(w0[c * 3 + 1]), wc = vg(w0[c * 3 + 2]);
        float bc = vg(b0[c]);
#pragma unroll
        for (int x = 0; x < 14; ++x) {
            float acc = bc;
            acc = fmaf(wa, g[x + 0], acc);
            acc = fmaf(wb, g[x + 1], acc);
            acc = fmaf(wc, g[x + 2], acc);
            ha[c][x] = fmaxf(acc, 0.0f);
        }
    }

    conv5<12>(ha, hb, w1, b1);   // 14 -> 12
    conv5<10>(hb, ha, w2, b2);   // 12 -> 10
    conv5<8> (ha, hb, w3, b3);   // 10 -> 8
    conv5<6> (hb, ha, w4, b4);   // 8  -> 6
    conv5<4> (ha, hb, w5, b5);   // 6  -> 4

    // Layer 6: 5 -> 1, width 4 -> 2
    float bias6 = vg(b6[0]);
    float t0 = bias6, t1 = bias6;
#pragma unroll
    for (int ci = 0; ci < 5; ++ci) {
        float wa = vg(w6[ci * 3 + 0]), wb = vg(w6[ci * 3 + 1]), wc = vg(w6[ci * 3 + 2]);
        t0 = fmaf(wa, hb[ci][0], t0);
        t0 = fmaf(wb, hb[ci][1], t0);
        t0 = fmaf(wc, hb[ci][2], t0);
        t1 = fmaf(wa, hb[ci][1], t1);
        t1 = fmaf(wb, hb[ci][2], t1);
        t1 = fmaf(wc, hb[ci][3], t1);
    }
    t0 = fmaxf(t0, 0.0f);
    t1 = fmaxf(t1, 0.0f);

    zout[(size_t)n * BB + lane] = 0.5f * (t0 + t1);
}

// ---------------------------------------------------------------------------
// Final driver gather: out[b, i] = z[driver_idx[i], b]   (out is (B, NDRV))
__global__ __launch_bounds__(256) void gather_out_kernel(
    const float* __restrict__ z, const int* __restrict__ didx,
    float* __restrict__ out)
{
    int i = blockIdx.x * 256 + threadIdx.x;
    if (i >= BB * NDRVN) return;
    int b = i / NDRVN;
    int k = i - b * NDRVN;
    out[i] = z[(size_t)didx[k] * BB + b];
}

// ---------------------------------------------------------------------------
extern "C" void kernel_launch(void* const* d_in, const int* in_sizes, int n_in,
                              void* d_out, int out_size, void* d_ws, size_t ws_size,
                              hipStream_t stream)
{
    const float* x    = (const float*)d_in[0];
    const int*   nidx = (const int*)  d_in[1];
    const int*   didx = (const int*)  d_in[2];
    const float* w[7];
    const float* b[7];
    for (int i = 0; i < 7; ++i) {
        w[i] = (const float*)d_in[3 + 2 * i];
        b[i] = (const float*)d_in[4 + 2 * i];
    }

    // Workspace: two ping-pong z buffers in (N, B) layout, 12.8 MB each.
    float* z0 = (float*)d_ws;
    float* z1 = z0 + (size_t)NB * BB;

    const int blocks = (NB * BB) / 256;   // 12500, exact

    transpose_kernel<<<blocks, 256, 0, stream>>>(x, z0);

    pass_kernel<<<blocks, 256, 0, stream>>>(z0, z1, nidx,
        w[0], b[0], w[1], b[1], w[2], b[2], w[3], b[3],
        w[4], b[4], w[5], b[5], w[6], b[6]);
    pass_kernel<<<blocks, 256, 0, stream>>>(z1, z0, nidx,
        w[0], b[0], w[1], b[1], w[2], b[2], w[3], b[3],
        w[4], b[4], w[5], b[5], w[6], b[6]);
    pass_kernel<<<blocks, 256, 0, stream>>>(z0, z1, nidx,
        w[0], b[0], w[1], b[1], w[2], b[2], w[3], b[3],
        w[4], b[4], w[5], b[5], w[6], b[6]);
    pass_kernel<<<blocks, 256, 0, stream>>>(z1, z0, nidx,
        w[0], b[0], w[1], b[1], w[2], b[2], w[3], b[3],
        w[4], b[4], w[5], b[5], w[6], b[6]);

    gather_out_kernel<<<(BB * NDRVN + 255) / 256, 256, 0, stream>>>(z0, didx, (float*)d_out);
}